// Round 6
// baseline (528.069 us; speedup 1.0000x reference)
//
#include <hip/hip_runtime.h>
#include <hip/hip_bf16.h>

#define N 8192
#define IN_C 256
#define OUT_C 64
#define ALPHA 0.2f
#define L2E 1.44269504f

typedef short bf16x8 __attribute__((ext_vector_type(8)));
typedef float f32x4 __attribute__((ext_vector_type(4)));
typedef unsigned long long u64;

// ---- ws layout (bytes) ----
#define OFF_H      0u            // f32  [8192][64]   h = x@w
#define OFF_HT     2097152u      // bf16 [64][8192]   h transposed
#define OFF_FS     3145728u      // f32  [8192]       f_src
#define OFF_FD     3178496u      // f32  [8192]       f_dst
#define OFF_FDMAX  3211264u      // f32  [1]
#define OFF_NUM    3211520u      // f32  [KQ][8192][64] partial numerators, den follows

// ---------------- h = x @ w  (+ fused f_src/f_dst) ----------------
__global__ __launch_bounds__(256) void k_linear(const float* __restrict__ x,
                                                const float* __restrict__ w,
                                                const float* __restrict__ a,
                                                float* __restrict__ h,
                                                float* __restrict__ fs,
                                                float* __restrict__ fd) {
    __shared__ float wl[IN_C * OUT_C];
    int t = threadIdx.x;
    for (int idx = t; idx < IN_C * OUT_C; idx += 256) wl[idx] = w[idx];
    __syncthreads();
    int i = blockIdx.x * 4 + (t >> 6);
    int c = t & 63;
    const float* xr = x + (size_t)i * IN_C;
    float acc = 0.f;
#pragma unroll 8
    for (int k = 0; k < IN_C; ++k) acc = fmaf(xr[k], wl[k * 64 + c], acc);
    h[(size_t)i * 64 + c] = acc;
    float s = acc * a[c];
    float d = acc * a[64 + c];
#pragma unroll
    for (int off = 32; off > 0; off >>= 1) {
        s += __shfl_xor(s, off, 64);
        d += __shfl_xor(d, off, 64);
    }
    if (c == 0) { fs[i] = s; fd[i] = d; }
}

// ---------------- h_t[c][i] = bf16(h[i][c]) ----------------
__global__ __launch_bounds__(256) void k_tr(const float* __restrict__ h,
                                            __hip_bfloat16* __restrict__ ht) {
    __shared__ __hip_bfloat16 lds[64 * 65];
    int t = threadIdx.x;
    int i0 = blockIdx.x * 64;
#pragma unroll
    for (int k = 0; k < 16; ++k) {
        int idx = k * 256 + t;
        int il = idx >> 6, c = idx & 63;
        lds[c * 65 + il] = __float2bfloat16(h[(size_t)(i0 + il) * 64 + c]);
    }
    __syncthreads();
#pragma unroll
    for (int k = 0; k < 16; ++k) {
        int idx = k * 256 + t;
        int c = idx >> 6, il = idx & 63;
        ht[(size_t)c * N + i0 + il] = lds[c * 65 + il];
    }
}

// ---------------- fd_max = max_j f_dst[j] ----------------
__global__ __launch_bounds__(256) void k_fdmax(const float* __restrict__ fd,
                                               float* __restrict__ out) {
    __shared__ float red[256];
    int t = threadIdx.x;
    float m = -3.4e38f;
    for (int j = t; j < N; j += 256) m = fmaxf(m, fd[j]);
    red[t] = m;
    __syncthreads();
    for (int s = 128; s > 0; s >>= 1) {
        if (t < s) red[t] = fmaxf(red[t], red[t + s]);
        __syncthreads();
    }
    if (t == 0) out[0] = red[0];
}

// ---------------- main kernel ----------------
// grid = KQ*128; bid = kq*128 + rb. Block: 64 rows x jch=N/KQ j-cols.
// Phase 1: pack adjacency 0/1 ints into an LDS bitmask with perfectly
//   sequential 1KB-per-instruction global reads + __ballot.  Per 256-col
//   group g and row: 4 u64 masks; mask_e bit l <-> col g*256 + 4*l + e.
// Phase 2: 4 waves x 16 rows, mfma_f32_16x16x32_bf16; A-frag weights
//   generated from LDS bits + fdst; B-frags from ht (global, L2-resident),
//   2-deep register prefetch. 5th MFMA vs all-ones B gives the denominator.
// LDS bit layout: row stride = groups*4+2 u64 (16B pad -> reads spread
//   across banks; same-(g,e) reads from 16 rows hit 16 distinct bank pairs).
struct HStage {
    float4 fd0, fd1;
    bf16x8 b0, b1, b2, b3;
};

__device__ __forceinline__ void load_h(HStage& s,
        const float* __restrict__ fdst,
        const unsigned short* __restrict__ pb0, const unsigned short* __restrict__ pb1,
        const unsigned short* __restrict__ pb2, const unsigned short* __restrict__ pb3,
        int jb) {
    s.fd0 = *(const float4*)(fdst + jb);
    s.fd1 = *(const float4*)(fdst + jb + 4);
    s.b0  = *(const bf16x8*)(pb0 + jb);
    s.b1  = *(const bf16x8*)(pb1 + jb);
    s.b2  = *(const bf16x8*)(pb2 + jb);
    s.b3  = *(const bf16x8*)(pb3 + jb);
}

__device__ __forceinline__ void compute_h(const HStage& s,
        u64 m0, u64 m1, u64 m2, u64 m3, int k8, int kg2,
        float fs, float mL, const bf16x8& bones,
        f32x4& acc0, f32x4& acc1, f32x4& acc2, f32x4& acc3, f32x4& acc4) {
    float fdv[8] = {s.fd0.x, s.fd0.y, s.fd0.z, s.fd0.w, s.fd1.x, s.fd1.y, s.fd1.z, s.fd1.w};
    u64 msel[4] = {m0, m1, m2, m3};
    bf16x8 af;
#pragma unroll
    for (int e = 0; e < 8; ++e) {
        // col within group = k8*32 + kg*8 + e ; mask = col&3 = e&3 (static),
        // bit = col>>2 = k8*8 + kg*2 + (e>>2)
        int sh = k8 * 8 + kg2 + (e >> 2);
        unsigned bit = (unsigned)(msel[e & 3] >> sh) & 1u;
        float ee = fs + fdv[e];
        float l  = fmaxf(ee, ALPHA * ee);          // leaky-relu
        float a2 = __builtin_fmaf(l, L2E, -mL);    // (l - m) * log2(e)
        float wt = __builtin_amdgcn_exp2f(a2);     // in (0, 1]
        wt = bit ? wt : 0.f;
        __hip_bfloat16 hb = __float2bfloat16(wt);
        union { __hip_bfloat16 b; short s16; } u; u.b = hb;
        af[e] = u.s16;
    }
    acc0 = __builtin_amdgcn_mfma_f32_16x16x32_bf16(af, s.b0, acc0, 0, 0, 0);
    acc1 = __builtin_amdgcn_mfma_f32_16x16x32_bf16(af, s.b1, acc1, 0, 0, 0);
    acc2 = __builtin_amdgcn_mfma_f32_16x16x32_bf16(af, s.b2, acc2, 0, 0, 0);
    acc3 = __builtin_amdgcn_mfma_f32_16x16x32_bf16(af, s.b3, acc3, 0, 0, 0);
    acc4 = __builtin_amdgcn_mfma_f32_16x16x32_bf16(af, bones, acc4, 0, 0, 0);
}

__global__ __launch_bounds__(256, 4) void k_main(
    const int* __restrict__ adj,
    const float* __restrict__ fsrc,
    const float* __restrict__ fdst,
    const float* __restrict__ fdmax_p,
    const unsigned short* __restrict__ ht,
    float* __restrict__ nump,
    float* __restrict__ denp_out,
    int jch, int ns, int groups) {
    __shared__ u64 bits[64 * 34];   // max: groups=8 -> stride 34 u64/row (17.4 KB)
    int bid = blockIdx.x;
    int rb = bid & 127;
    int kq = bid >> 7;
    int t = threadIdx.x;
    int w = t >> 6;
    int l = t & 63;
    int r  = l & 15;
    int kg = l >> 4;
    int kg2 = kg * 2;
    int ib0 = rb * 64;
    int i  = ib0 + w * 16 + r;      // this lane's output row
    int j0 = kq * jch;
    int strideU = groups * 4 + 2;

    // ---- phase 1: pack adjacency into LDS bitmask (sequential reads) ----
    for (int rr2 = 0; rr2 < 16; ++rr2) {
        int rowL = w * 16 + rr2;
        const int* src = adj + (size_t)(ib0 + rowL) * N + j0;
        for (int g = 0; g < groups; ++g) {
            int4 v = *(const int4*)(src + g * 256 + l * 4);
            u64 b0 = __ballot(v.x > 0);
            u64 b1 = __ballot(v.y > 0);
            u64 b2 = __ballot(v.z > 0);
            u64 b3 = __ballot(v.w > 0);
            if (l == 0) {
                u64* p = &bits[rowL * strideU + g * 4];
                p[0] = b0; p[1] = b1; p[2] = b2; p[3] = b3;
            }
        }
    }
    __syncthreads();

    // ---- phase 2: MFMA from LDS bits + global ht/fd ----
    float fs  = fsrc[i];
    float fdm = *fdmax_p;
    float e0  = fs + fdm;
    float m   = fmaxf(e0, ALPHA * e0);   // row-wise softmax shift (monotone in fd)
    float mL  = m * L2E;

    const unsigned short* pb0 = ht + (size_t)(r)      * N;
    const unsigned short* pb1 = ht + (size_t)(16 + r) * N;
    const unsigned short* pb2 = ht + (size_t)(32 + r) * N;
    const unsigned short* pb3 = ht + (size_t)(48 + r) * N;

    bf16x8 bones;
#pragma unroll
    for (int e = 0; e < 8; ++e) bones[e] = (short)0x3F80;  // bf16 1.0

    f32x4 acc0 = {0.f,0.f,0.f,0.f}, acc1 = {0.f,0.f,0.f,0.f};
    f32x4 acc2 = {0.f,0.f,0.f,0.f}, acc3 = {0.f,0.f,0.f,0.f};
    f32x4 acc4 = {0.f,0.f,0.f,0.f};

    int base = j0 + kg * 8;
    int rowL = w * 16 + r;
    HStage A, B;
    load_h(A, fdst, pb0, pb1, pb2, pb3, base);
    load_h(B, fdst, pb0, pb1, pb2, pb3, base + 32);

#pragma unroll 1
    for (int g = 0; g < groups; ++g) {
        const u64* mp = &bits[rowL * strideU + g * 4];
        u64 m0 = mp[0], m1 = mp[1], m2 = mp[2], m3 = mp[3];
#pragma unroll
        for (int k8 = 0; k8 < 8; ++k8) {
            int ks = g * 8 + k8;
            int nxt = ks + 2 < ns ? ks + 2 : 0;   // wrap: safe, branch-free
            if (k8 & 1) {
                compute_h(B, m0, m1, m2, m3, k8, kg2, fs, mL, bones,
                          acc0, acc1, acc2, acc3, acc4);
                load_h(B, fdst, pb0, pb1, pb2, pb3, base + nxt * 32);
            } else {
                compute_h(A, m0, m1, m2, m3, k8, kg2, fs, mL, bones,
                          acc0, acc1, acc2, acc3, acc4);
                load_h(A, fdst, pb0, pb1, pb2, pb3, base + nxt * 32);
            }
        }
    }

    // numerator partials: D layout col=lane&15, row=(lane>>4)*4+reg
    int orow = ib0 + w * 16 + kg * 4;
    float* np = nump + (size_t)kq * N * 64;
#pragma unroll
    for (int rr = 0; rr < 4; ++rr) {
        np[(size_t)(orow + rr) * 64 + 0 * 16 + r] = acc0[rr];
        np[(size_t)(orow + rr) * 64 + 1 * 16 + r] = acc1[rr];
        np[(size_t)(orow + rr) * 64 + 2 * 16 + r] = acc2[rr];
        np[(size_t)(orow + rr) * 64 + 3 * 16 + r] = acc3[rr];
    }
    // denominator: every lane holds den for rows orow..orow+3 in acc4
    if (r == 0) {
#pragma unroll
        for (int rr = 0; rr < 4; ++rr) denp_out[kq * N + orow + rr] = acc4[rr];
    }
}

// ---------------- out = elu(num/den), float4 per thread ----------------
__global__ __launch_bounds__(256) void k_final(const float* __restrict__ nump,
                                               const float* __restrict__ denp,
                                               float* __restrict__ out,
                                               int kqn) {
    int gid = blockIdx.x * 256 + threadIdx.x;   // 0 .. 131071
    int base = gid * 4;
    int i = base >> 6;
    float4 num = {0.f, 0.f, 0.f, 0.f};
    float den = 0.f;
    for (int q = 0; q < kqn; ++q) {
        float4 v = *(const float4*)(nump + (size_t)q * (N * 64) + base);
        num.x += v.x; num.y += v.y; num.z += v.z; num.w += v.w;
        den += denp[q * N + i];
    }
    float rd = 1.f / den;
    float4 o;
    o.x = num.x * rd; o.y = num.y * rd; o.z = num.z * rd; o.w = num.w * rd;
    o.x = o.x > 0.f ? o.x : __expf(o.x) - 1.f;
    o.y = o.y > 0.f ? o.y : __expf(o.y) - 1.f;
    o.z = o.z > 0.f ? o.z : __expf(o.z) - 1.f;
    o.w = o.w > 0.f ? o.w : __expf(o.w) - 1.f;
    *(float4*)(out + base) = o;
}

extern "C" void kernel_launch(void* const* d_in, const int* in_sizes, int n_in,
                              void* d_out, int out_size, void* d_ws, size_t ws_size,
                              hipStream_t stream) {
    const float* x   = (const float*)d_in[0];
    const int*   adj = (const int*)d_in[1];
    const float* w   = (const float*)d_in[2];
    const float* a   = (const float*)d_in[3];
    float* out = (float*)d_out;
    char*  ws  = (char*)d_ws;

    float*          h    = (float*)(ws + OFF_H);
    __hip_bfloat16* ht   = (__hip_bfloat16*)(ws + OFF_HT);
    float*          fs   = (float*)(ws + OFF_FS);
    float*          fd   = (float*)(ws + OFF_FD);
    float*          fdm  = (float*)(ws + OFF_FDMAX);
    float*          nump = (float*)(ws + OFF_NUM);

    size_t need8 = (size_t)OFF_NUM + 8ull * N * 64 * 4 + 8ull * N * 4;
    int KQ = (ws_size >= need8) ? 8 : 4;
    float* denp = nump + (size_t)KQ * N * 64;
    int jch = N / KQ;
    int ns  = jch / 32;
    int groups = jch / 256;

    k_linear<<<2048, 256, 0, stream>>>(x, w, a, h, fs, fd);
    k_tr<<<128, 256, 0, stream>>>(h, ht);
    k_fdmax<<<1, 256, 0, stream>>>(fd, fdm);
    k_main<<<KQ * 128, 256, 0, stream>>>(adj, fs, fd, fdm,
                                         (const unsigned short*)ht, nump, denp,
                                         jch, ns, groups);
    k_final<<<512, 256, 0, stream>>>(nump, denp, out, KQ);
}

// Round 7
// 511.835 us; speedup vs baseline: 1.0317x; 1.0317x over previous
//
#include <hip/hip_runtime.h>
#include <hip/hip_bf16.h>

#define N 8192
#define IN_C 256
#define OUT_C 64
#define ALPHA 0.2f
#define L2E 1.44269504f

typedef short bf16x8 __attribute__((ext_vector_type(8)));
typedef float f32x4 __attribute__((ext_vector_type(4)));
typedef unsigned long long u64;

// ---- ws layout (bytes) ----
#define OFF_H      0u            // f32  [8192][64]    h = x@w
#define OFF_HT     2097152u      // bf16 [256*4*64*8]  h in MFMA B-fragment order (1 MB)
#define OFF_FS     3145728u      // f32  [8192]        f_src
#define OFF_FD     3178496u      // f32  [8192]        f_dst
#define OFF_FDMAX  3211264u      // f32  [1]
#define OFF_BITS   3211520u      // u64  [8192][128]   packed adjacency (8 MB)
#define OFF_NUM    11600128u     // f32  [KQ][8192][64] partial numerators, den follows

// ---------------- h = x @ w  (+ fused f_src/f_dst) ----------------
__global__ __launch_bounds__(256) void k_linear(const float* __restrict__ x,
                                                const float* __restrict__ w,
                                                const float* __restrict__ a,
                                                float* __restrict__ h,
                                                float* __restrict__ fs,
                                                float* __restrict__ fd) {
    __shared__ float wl[IN_C * OUT_C];
    int t = threadIdx.x;
    for (int idx = t; idx < IN_C * OUT_C; idx += 256) wl[idx] = w[idx];
    __syncthreads();
    int i = blockIdx.x * 4 + (t >> 6);
    int c = t & 63;
    const float* xr = x + (size_t)i * IN_C;
    float acc = 0.f;
#pragma unroll 8
    for (int k = 0; k < IN_C; ++k) acc = fmaf(xr[k], wl[k * 64 + c], acc);
    h[(size_t)i * 64 + c] = acc;
    float s = acc * a[c];
    float d = acc * a[64 + c];
#pragma unroll
    for (int off = 32; off > 0; off >>= 1) {
        s += __shfl_xor(s, off, 64);
        d += __shfl_xor(d, off, 64);
    }
    if (c == 0) { fs[i] = s; fd[i] = d; }
}

// ---------------- htf: h in MFMA B-fragment order ----------------
// htf[((ks*4 + ct)*64 + lane)*8 + e] = bf16(h[node = ks*32 + (lane>>4)*8 + e][ch = ct*16 + (lane&15)])
// => k_mfma's B-loads are lane-contiguous 16B with wave-uniform offsets.
__global__ __launch_bounds__(256) void k_frag(const float* __restrict__ h,
                                              unsigned short* __restrict__ htf) {
    __shared__ float lds[64 * 65];   // [ch][node_local], +1 pad
    int t = threadIdx.x;
    int i0 = blockIdx.x * 64;
#pragma unroll
    for (int k = 0; k < 16; ++k) {
        int idx = k * 256 + t;
        int il = idx >> 6, c = idx & 63;           // read h[i0+il][c], coalesced in c
        lds[c * 65 + il] = h[(size_t)(i0 + il) * 64 + c];
    }
    __syncthreads();
    int l = t & 63;
    int ct = t >> 6;                               // wave owns one ct
    int r = l & 15, kg = l >> 4;
    int ch = ct * 16 + r;
#pragma unroll
    for (int ksl = 0; ksl < 2; ++ksl) {
        int ks = blockIdx.x * 2 + ksl;
        int n0 = ksl * 32 + kg * 8;
        bf16x8 v;
#pragma unroll
        for (int e = 0; e < 8; ++e) {
            __hip_bfloat16 hb = __float2bfloat16(lds[ch * 65 + n0 + e]);
            union { __hip_bfloat16 b; short s16; } u; u.b = hb;
            v[e] = u.s16;
        }
        *(bf16x8*)(htf + ((size_t)(ks * 4 + ct) * 64 + l) * 8) = v;  // 1KB/wave store
    }
}

// ---------------- fd_max = max_j f_dst[j] ----------------
__global__ __launch_bounds__(256) void k_fdmax(const float* __restrict__ fd,
                                               float* __restrict__ out) {
    __shared__ float red[256];
    int t = threadIdx.x;
    float m = -3.4e38f;
    for (int j = t; j < N; j += 256) m = fmaxf(m, fd[j]);
    red[t] = m;
    __syncthreads();
    for (int s = 128; s > 0; s >>= 1) {
        if (t < s) red[t] = fmaxf(red[t], red[t + s]);
        __syncthreads();
    }
    if (t == 0) out[0] = red[0];
}

// ---------------- adjacency -> packed bitmask (pure stream) ----------------
// chunk c = row*32 + gg covers cols gg*256 + 4l + m; bits[c*4+m] bit l.
__global__ __launch_bounds__(256) void k_pack(const int* __restrict__ adj,
                                              u64* __restrict__ bits) {
    const int NW = 2048 * 4;                     // total waves in grid
    int t = threadIdx.x;
    int l = t & 63;
    int wv = (blockIdx.x * 256 + t) >> 6;        // global wave id
#pragma unroll 1
    for (int c = wv; c < (N / 256) * N / 1; c += 2 * NW) {   // 262144 chunks
        int4 v0 = *(const int4*)(adj + (size_t)c * 256 + l * 4);
        int4 v1 = *(const int4*)(adj + (size_t)(c + NW) * 256 + l * 4);
        u64 a0 = __ballot(v0.x > 0), a1 = __ballot(v0.y > 0);
        u64 a2 = __ballot(v0.z > 0), a3 = __ballot(v0.w > 0);
        u64 b0 = __ballot(v1.x > 0), b1 = __ballot(v1.y > 0);
        u64 b2 = __ballot(v1.z > 0), b3 = __ballot(v1.w > 0);
        if (l == 0) {
            u64* q0 = bits + (size_t)c * 4;
            q0[0] = a0; q0[1] = a1; q0[2] = a2; q0[3] = a3;
            u64* q1 = bits + (size_t)(c + NW) * 4;
            q1[0] = b0; q1[1] = b1; q1[2] = b2; q1[3] = b3;
        }
    }
}

// ---------------- MFMA kernel ----------------
// grid = KQ*128; bid = kq*128 + rb. Block: 64 rows x jch=N/KQ cols.
// Bit slice loaded global->LDS; weights generated from bits + fdst;
// B-frags from htf (coalesced, L2-hot). 5th MFMA vs ones = denominator.
struct HStage {
    float4 fd0, fd1;
    bf16x8 b0, b1, b2, b3;
};

__device__ __forceinline__ void load_h2(HStage& s,
        const float* __restrict__ fdst,
        const unsigned short* __restrict__ hb,   // htf + lane*8
        int jb, int ksg) {
    s.fd0 = *(const float4*)(fdst + jb);
    s.fd1 = *(const float4*)(fdst + jb + 4);
    const unsigned short* p = hb + (size_t)ksg * 2048;
    s.b0 = *(const bf16x8*)(p);
    s.b1 = *(const bf16x8*)(p + 512);
    s.b2 = *(const bf16x8*)(p + 1024);
    s.b3 = *(const bf16x8*)(p + 1536);
}

__device__ __forceinline__ void compute_h(const HStage& s,
        u64 m0, u64 m1, u64 m2, u64 m3, int k8, int kg2,
        float fs, float mL, const bf16x8& bones,
        f32x4& acc0, f32x4& acc1, f32x4& acc2, f32x4& acc3, f32x4& acc4) {
    float fdv[8] = {s.fd0.x, s.fd0.y, s.fd0.z, s.fd0.w, s.fd1.x, s.fd1.y, s.fd1.z, s.fd1.w};
    u64 msel[4] = {m0, m1, m2, m3};
    bf16x8 af;
#pragma unroll
    for (int e = 0; e < 8; ++e) {
        // col within group = k8*32 + kg*8 + e ; mask idx = e&3, bit = k8*8 + kg*2 + (e>>2)
        int sh = k8 * 8 + kg2 + (e >> 2);
        unsigned bit = (unsigned)(msel[e & 3] >> sh) & 1u;
        float ee = fs + fdv[e];
        float l  = fmaxf(ee, ALPHA * ee);          // leaky-relu
        float a2 = __builtin_fmaf(l, L2E, -mL);    // (l - m) * log2(e)
        float wt = __builtin_amdgcn_exp2f(a2);     // in (0, 1]
        wt = bit ? wt : 0.f;
        __hip_bfloat16 hb = __float2bfloat16(wt);
        union { __hip_bfloat16 b; short s16; } u; u.b = hb;
        af[e] = u.s16;
    }
    acc0 = __builtin_amdgcn_mfma_f32_16x16x32_bf16(af, s.b0, acc0, 0, 0, 0);
    acc1 = __builtin_amdgcn_mfma_f32_16x16x32_bf16(af, s.b1, acc1, 0, 0, 0);
    acc2 = __builtin_amdgcn_mfma_f32_16x16x32_bf16(af, s.b2, acc2, 0, 0, 0);
    acc3 = __builtin_amdgcn_mfma_f32_16x16x32_bf16(af, s.b3, acc3, 0, 0, 0);
    acc4 = __builtin_amdgcn_mfma_f32_16x16x32_bf16(af, bones, acc4, 0, 0, 0);
}

__global__ __launch_bounds__(256, 4) void k_mfma(
    const u64* __restrict__ bitsg,
    const float* __restrict__ fsrc,
    const float* __restrict__ fdst,
    const float* __restrict__ fdmax_p,
    const unsigned short* __restrict__ htf,
    float* __restrict__ nump,
    float* __restrict__ denp_out,
    int jch, int ns, int groups) {
    __shared__ u64 bits[64 * 34];
    int bid = blockIdx.x;
    int rb = bid & 127, kq = bid >> 7;
    int t = threadIdx.x, w = t >> 6, l = t & 63;
    int r = l & 15, kg = l >> 4, kg2 = kg * 2;
    int ib0 = rb * 64;
    int i = ib0 + w * 16 + r;
    int j0 = kq * jch;
    int strideU = groups * 4 + 2;
    int gw = groups * 4;                  // u64 per row in this slice
    int gbase4 = (j0 >> 8) * 4;

    // load bit slice -> LDS (coalesced 128B-per-row segments, L2/L3-hot)
    for (int u = t; u < 64 * gw; u += 256) {
        int rowL = u / gw, rem = u - rowL * gw;
        bits[rowL * strideU + rem] = bitsg[(size_t)(ib0 + rowL) * 128 + gbase4 + rem];
    }
    __syncthreads();

    float fs  = fsrc[i];
    float fdm = *fdmax_p;
    float e0  = fs + fdm;
    float m   = fmaxf(e0, ALPHA * e0);    // row-wise softmax shift (monotone in fd)
    float mL  = m * L2E;

    const unsigned short* hb = htf + l * 8;
    int ks0 = j0 >> 5;                    // global k-step base

    bf16x8 bones;
#pragma unroll
    for (int e = 0; e < 8; ++e) bones[e] = (short)0x3F80;  // bf16 1.0

    f32x4 acc0 = {0.f,0.f,0.f,0.f}, acc1 = {0.f,0.f,0.f,0.f};
    f32x4 acc2 = {0.f,0.f,0.f,0.f}, acc3 = {0.f,0.f,0.f,0.f};
    f32x4 acc4 = {0.f,0.f,0.f,0.f};

    int baseJ = j0 + kg * 8;
    int rowL = w * 16 + r;
    HStage A, B;
    load_h2(A, fdst, hb, baseJ, ks0);
    load_h2(B, fdst, hb, baseJ + 32, ks0 + 1);

#pragma unroll 1
    for (int g = 0; g < groups; ++g) {
        const u64* mp = &bits[rowL * strideU + g * 4];
        u64 m0 = mp[0], m1 = mp[1], m2 = mp[2], m3 = mp[3];
#pragma unroll
        for (int k8 = 0; k8 < 8; ++k8) {
            int ks = g * 8 + k8;
            int nxt = ks + 2 < ns ? ks + 2 : 0;   // wrap: safe, branch-free
            if (k8 & 1) {
                compute_h(B, m0, m1, m2, m3, k8, kg2, fs, mL, bones,
                          acc0, acc1, acc2, acc3, acc4);
                load_h2(B, fdst, hb, baseJ + nxt * 32, ks0 + nxt);
            } else {
                compute_h(A, m0, m1, m2, m3, k8, kg2, fs, mL, bones,
                          acc0, acc1, acc2, acc3, acc4);
                load_h2(A, fdst, hb, baseJ + nxt * 32, ks0 + nxt);
            }
        }
    }

    // numerator partials: D layout col=lane&15, row=(lane>>4)*4+reg
    int orow = ib0 + w * 16 + kg * 4;
    float* np = nump + (size_t)kq * N * 64;
#pragma unroll
    for (int rr = 0; rr < 4; ++rr) {
        np[(size_t)(orow + rr) * 64 + 0 * 16 + r] = acc0[rr];
        np[(size_t)(orow + rr) * 64 + 1 * 16 + r] = acc1[rr];
        np[(size_t)(orow + rr) * 64 + 2 * 16 + r] = acc2[rr];
        np[(size_t)(orow + rr) * 64 + 3 * 16 + r] = acc3[rr];
    }
    if (r == 0) {
#pragma unroll
        for (int rr = 0; rr < 4; ++rr) denp_out[kq * N + orow + rr] = acc4[rr];
    }
}

// ---------------- out = elu(num/den), float4 per thread ----------------
__global__ __launch_bounds__(256) void k_final(const float* __restrict__ nump,
                                               const float* __restrict__ denp,
                                               float* __restrict__ out,
                                               int kqn) {
    int gid = blockIdx.x * 256 + threadIdx.x;   // 0 .. 131071
    int base = gid * 4;
    int i = base >> 6;
    float4 num = {0.f, 0.f, 0.f, 0.f};
    float den = 0.f;
    for (int q = 0; q < kqn; ++q) {
        float4 v = *(const float4*)(nump + (size_t)q * (N * 64) + base);
        num.x += v.x; num.y += v.y; num.z += v.z; num.w += v.w;
        den += denp[q * N + i];
    }
    float rd = 1.f / den;
    float4 o;
    o.x = num.x * rd; o.y = num.y * rd; o.z = num.z * rd; o.w = num.w * rd;
    o.x = o.x > 0.f ? o.x : __expf(o.x) - 1.f;
    o.y = o.y > 0.f ? o.y : __expf(o.y) - 1.f;
    o.z = o.z > 0.f ? o.z : __expf(o.z) - 1.f;
    o.w = o.w > 0.f ? o.w : __expf(o.w) - 1.f;
    *(float4*)(out + base) = o;
}

extern "C" void kernel_launch(void* const* d_in, const int* in_sizes, int n_in,
                              void* d_out, int out_size, void* d_ws, size_t ws_size,
                              hipStream_t stream) {
    const float* x   = (const float*)d_in[0];
    const int*   adj = (const int*)d_in[1];
    const float* w   = (const float*)d_in[2];
    const float* a   = (const float*)d_in[3];
    float* out = (float*)d_out;
    char*  ws  = (char*)d_ws;

    float*          h    = (float*)(ws + OFF_H);
    unsigned short* htf  = (unsigned short*)(ws + OFF_HT);
    float*          fs   = (float*)(ws + OFF_FS);
    float*          fd   = (float*)(ws + OFF_FD);
    float*          fdm  = (float*)(ws + OFF_FDMAX);
    u64*            bits = (u64*)(ws + OFF_BITS);
    float*          nump = (float*)(ws + OFF_NUM);

    size_t need8 = (size_t)OFF_NUM + 8ull * N * 64 * 4 + 8ull * N * 4;
    int KQ = (ws_size >= need8) ? 8 : 4;
    float* denp = nump + (size_t)KQ * N * 64;
    int jch = N / KQ;
    int ns  = jch / 32;
    int groups = jch / 256;

    k_linear<<<2048, 256, 0, stream>>>(x, w, a, h, fs, fd);
    k_frag<<<128, 256, 0, stream>>>(h, htf);
    k_fdmax<<<1, 256, 0, stream>>>(fd, fdm);
    k_pack<<<2048, 256, 0, stream>>>(adj, bits);
    k_mfma<<<KQ * 128, 256, 0, stream>>>(bits, fs, fd, fdm, htf, nump, denp,
                                         jch, ns, groups);
    k_final<<<512, 256, 0, stream>>>(nump, denp, out, KQ);
}

// Round 9
// 500.417 us; speedup vs baseline: 1.0553x; 1.0228x over previous
//
#include <hip/hip_runtime.h>
#include <hip/hip_bf16.h>

#define N 8192
#define IN_C 256
#define OUT_C 64
#define ALPHA 0.2f
#define L2E 1.44269504f

typedef short bf16x8 __attribute__((ext_vector_type(8)));
typedef float f32x4 __attribute__((ext_vector_type(4)));
typedef unsigned long long u64;

// ---- ws layout (bytes) ----
#define OFF_H      0u            // f32  [8192][64]    h = x@w
#define OFF_HT     2097152u      // bf16 [256*4*64*8]  h in MFMA B-fragment order (1 MB)
#define OFF_FS     3145728u      // f32  [8192]        f_src
#define OFF_FD     3178496u      // f32  [8192]        f_dst
#define OFF_FDMAX  3211264u      // f32  [1]
#define OFF_BITS   3211520u      // u64  [8192][128]   packed adjacency (8 MB)
#define OFF_NUM    11600128u     // f32  [KQ][8192][64] partial numerators, den follows

// ---------------- h = x @ w  (+ fused f_src/f_dst) ----------------
__global__ __launch_bounds__(256) void k_linear(const float* __restrict__ x,
                                                const float* __restrict__ w,
                                                const float* __restrict__ a,
                                                float* __restrict__ h,
                                                float* __restrict__ fs,
                                                float* __restrict__ fd) {
    __shared__ float wl[IN_C * OUT_C];
    int t = threadIdx.x;
    for (int idx = t; idx < IN_C * OUT_C; idx += 256) wl[idx] = w[idx];
    __syncthreads();
    int i = blockIdx.x * 4 + (t >> 6);
    int c = t & 63;
    const float* xr = x + (size_t)i * IN_C;
    float acc = 0.f;
#pragma unroll 8
    for (int k = 0; k < IN_C; ++k) acc = fmaf(xr[k], wl[k * 64 + c], acc);
    h[(size_t)i * 64 + c] = acc;
    float s = acc * a[c];
    float d = acc * a[64 + c];
#pragma unroll
    for (int off = 32; off > 0; off >>= 1) {
        s += __shfl_xor(s, off, 64);
        d += __shfl_xor(d, off, 64);
    }
    if (c == 0) { fs[i] = s; fd[i] = d; }
}

// ---------------- htf: h in MFMA B-fragment order ----------------
// htf[((ks*4 + ct)*64 + lane)*8 + e] = bf16(h[ks*32 + (lane>>4)*8 + e][ct*16 + (lane&15)])
__global__ __launch_bounds__(256) void k_frag(const float* __restrict__ h,
                                              unsigned short* __restrict__ htf) {
    __shared__ float lds[64 * 65];
    int t = threadIdx.x;
    int i0 = blockIdx.x * 64;
#pragma unroll
    for (int k = 0; k < 16; ++k) {
        int idx = k * 256 + t;
        int il = idx >> 6, c = idx & 63;
        lds[c * 65 + il] = h[(size_t)(i0 + il) * 64 + c];
    }
    __syncthreads();
    int l = t & 63;
    int ct = t >> 6;
    int r = l & 15, kg = l >> 4;
    int ch = ct * 16 + r;
#pragma unroll
    for (int ksl = 0; ksl < 2; ++ksl) {
        int ks = blockIdx.x * 2 + ksl;
        int n0 = ksl * 32 + kg * 8;
        bf16x8 v;
#pragma unroll
        for (int e = 0; e < 8; ++e) {
            __hip_bfloat16 hb = __float2bfloat16(lds[ch * 65 + n0 + e]);
            union { __hip_bfloat16 b; short s16; } u; u.b = hb;
            v[e] = u.s16;
        }
        *(bf16x8*)(htf + ((size_t)(ks * 4 + ct) * 64 + l) * 8) = v;
    }
}

// ---------------- fd_max ----------------
__global__ __launch_bounds__(256) void k_fdmax(const float* __restrict__ fd,
                                               float* __restrict__ out) {
    __shared__ float red[256];
    int t = threadIdx.x;
    float m = -3.4e38f;
    for (int j = t; j < N; j += 256) m = fmaxf(m, fd[j]);
    red[t] = m;
    __syncthreads();
    for (int s = 128; s > 0; s >>= 1) {
        if (t < s) red[t] = fmaxf(red[t], red[t + s]);
        __syncthreads();
    }
    if (t == 0) out[0] = red[0];
}

// ---------------- adjacency -> packed bits (pure stream, 4-deep) ----------------
// chunk c covers adj[c*256 + 4l + m]; bits[c*4+m] bit l.
__global__ __launch_bounds__(256) void k_pack(const int* __restrict__ adj,
                                              u64* __restrict__ bits) {
    int t = threadIdx.x, l = t & 63;
    int wv = (blockIdx.x * 256 + t) >> 6;        // 0..8191
    const int NWV = 2048 * 4;
#pragma unroll 1
    for (int base = wv * 4; base < 262144; base += NWV * 4) {
        int4 v0 = *(const int4*)(adj + (size_t)(base + 0) * 256 + l * 4);
        int4 v1 = *(const int4*)(adj + (size_t)(base + 1) * 256 + l * 4);
        int4 v2 = *(const int4*)(adj + (size_t)(base + 2) * 256 + l * 4);
        int4 v3 = *(const int4*)(adj + (size_t)(base + 3) * 256 + l * 4);
        u64 b00 = __ballot(v0.x > 0), b01 = __ballot(v0.y > 0);
        u64 b02 = __ballot(v0.z > 0), b03 = __ballot(v0.w > 0);
        u64 b10 = __ballot(v1.x > 0), b11 = __ballot(v1.y > 0);
        u64 b12 = __ballot(v1.z > 0), b13 = __ballot(v1.w > 0);
        u64 b20 = __ballot(v2.x > 0), b21 = __ballot(v2.y > 0);
        u64 b22 = __ballot(v2.z > 0), b23 = __ballot(v2.w > 0);
        u64 b30 = __ballot(v3.x > 0), b31 = __ballot(v3.y > 0);
        u64 b32 = __ballot(v3.z > 0), b33 = __ballot(v3.w > 0);
        if (l == 0) {
            u64* q = bits + (size_t)base * 4;
            q[0] = b00; q[1] = b01; q[2]  = b02; q[3]  = b03;
            q[4] = b10; q[5] = b11; q[6]  = b12; q[7]  = b13;
            q[8] = b20; q[9] = b21; q[10] = b22; q[11] = b23;
            q[12] = b30; q[13] = b31; q[14] = b32; q[15] = b33;
        }
    }
}

// ---------------- MFMA kernel (LDS ring pipeline) ----------------
// grid = KQ*128; block: 64 rows x jch cols. B-tiles (4KB/k-step) stream
// global->LDS via global_load_lds, 4-buffer ring, 3 stages in flight,
// counted vmcnt(2) + raw s_barrier per k-step (vmcnt 1/0 peeled tail).
__device__ __forceinline__ void stage16(const unsigned short* g, unsigned short* lds) {
    __builtin_amdgcn_global_load_lds(
        (const __attribute__((address_space(1))) unsigned int*)g,
        (__attribute__((address_space(3))) unsigned int*)lds, 16, 0, 0);
}

__global__ __launch_bounds__(256, 4) void k_mfma(
    const u64* __restrict__ bitsg,
    const float* __restrict__ fsrc,
    const float* __restrict__ fdst,
    const float* __restrict__ fdmax_p,
    const unsigned short* __restrict__ htf,
    float* __restrict__ nump,
    float* __restrict__ denp_out,
    int jch, int ns, int groups) {
    __shared__ u64 bits[64 * 34];                       // 17408 B
    __shared__ float fd_lds[1024];                      // 4096 B (KQ=8 path)
    __shared__ alignas(16) unsigned short bufs[4][2048];// 16384 B ring
    int bid = blockIdx.x;
    int rb = bid & 127, kq = bid >> 7;
    int t = threadIdx.x, w = t >> 6, l = t & 63;
    int r = l & 15, kg = l >> 4, kg2 = kg * 2;
    int ib0 = rb * 64;
    int i = ib0 + w * 16 + r;
    int j0 = kq * jch;
    int strideU = groups * 4 + 2;
    int gw = groups * 4;
    int gbase4 = (j0 >> 8) * 4;
    bool fdl = (jch <= 1024);

    // stage bits + fd slice -> LDS
    for (int u = t; u < 64 * gw; u += 256) {
        int rowL = u / gw, rem = u - rowL * gw;
        bits[rowL * strideU + rem] = bitsg[(size_t)(ib0 + rowL) * 128 + gbase4 + rem];
    }
    if (fdl) for (int u = t; u < jch; u += 256) fd_lds[u] = fdst[j0 + u];
    __syncthreads();

    float fs  = fsrc[i];
    float fdm = *fdmax_p;
    float e0  = fs + fdm;
    float m   = fmaxf(e0, ALPHA * e0);   // row-wise softmax shift (monotone in fd)
    float mL  = m * L2E;

    int ks0 = j0 >> 5;
    // prologue: 3 stages in flight
    stage16(htf + ((size_t)(ks0 + 0) * 2048 + t * 8), &bufs[0][w * 512]);
    stage16(htf + ((size_t)(ks0 + 1) * 2048 + t * 8), &bufs[1][w * 512]);
    stage16(htf + ((size_t)(ks0 + 2) * 2048 + t * 8), &bufs[2][w * 512]);

    bf16x8 bones;
#pragma unroll
    for (int e = 0; e < 8; ++e) bones[e] = (short)0x3F80;  // bf16 1.0

    f32x4 acc0 = {0.f,0.f,0.f,0.f}, acc1 = {0.f,0.f,0.f,0.f};
    f32x4 acc2 = {0.f,0.f,0.f,0.f}, acc3 = {0.f,0.f,0.f,0.f};
    f32x4 acc4 = {0.f,0.f,0.f,0.f};

    int rowL = w * 16 + r;
#pragma unroll 1
    for (int g = 0; g < groups; ++g) {
        const u64* mp = &bits[rowL * strideU + g * 4];
        u64 m0 = mp[0], m1 = mp[1], m2 = mp[2], m3 = mp[3];
        u64 msel[4] = {m0, m1, m2, m3};
#pragma unroll
        for (int k8 = 0; k8 < 8; ++k8) {
            int ks = g * 8 + k8;
            // wait for stage ks, then sync all waves' stages
            if (ks < ns - 2)       asm volatile("s_waitcnt vmcnt(2)" ::: "memory");
            else if (ks == ns - 2) asm volatile("s_waitcnt vmcnt(1)" ::: "memory");
            else                   asm volatile("s_waitcnt vmcnt(0)" ::: "memory");
            asm volatile("s_barrier" ::: "memory");
            if (ks + 3 < ns)
                stage16(htf + ((size_t)(ks0 + ks + 3) * 2048 + t * 8),
                        &bufs[(ks + 3) & 3][w * 512]);

            const unsigned short* bp = &bufs[ks & 3][0];
            bf16x8 b0 = *(const bf16x8*)(bp + (0 * 64 + l) * 8);
            bf16x8 b1 = *(const bf16x8*)(bp + (1 * 64 + l) * 8);
            bf16x8 b2 = *(const bf16x8*)(bp + (2 * 64 + l) * 8);
            bf16x8 b3 = *(const bf16x8*)(bp + (3 * 64 + l) * 8);
            float4 fd0, fd1;
            if (fdl) {
                fd0 = *(const float4*)(fd_lds + ks * 32 + kg * 8);
                fd1 = *(const float4*)(fd_lds + ks * 32 + kg * 8 + 4);
            } else {
                fd0 = *(const float4*)(fdst + j0 + ks * 32 + kg * 8);
                fd1 = *(const float4*)(fdst + j0 + ks * 32 + kg * 8 + 4);
            }
            float fdv[8] = {fd0.x, fd0.y, fd0.z, fd0.w, fd1.x, fd1.y, fd1.z, fd1.w};
            bf16x8 af;
#pragma unroll
            for (int e = 0; e < 8; ++e) {
                // col in group = k8*32 + kg*8 + e; mask idx = e&3, bit = k8*8 + kg*2 + (e>>2)
                int sh = k8 * 8 + kg2 + (e >> 2);
                unsigned bit = (unsigned)(msel[e & 3] >> sh) & 1u;
                float ee = fs + fdv[e];
                float lv = fmaxf(ee, ALPHA * ee);          // leaky-relu
                float a2 = __builtin_fmaf(lv, L2E, -mL);   // (l - m)*log2e
                float wt = __builtin_amdgcn_exp2f(a2);     // (0,1]
                wt = bit ? wt : 0.f;
                __hip_bfloat16 hb = __float2bfloat16(wt);
                union { __hip_bfloat16 b; short s16; } u; u.b = hb;
                af[e] = u.s16;
            }
            acc0 = __builtin_amdgcn_mfma_f32_16x16x32_bf16(af, b0, acc0, 0, 0, 0);
            acc1 = __builtin_amdgcn_mfma_f32_16x16x32_bf16(af, b1, acc1, 0, 0, 0);
            acc2 = __builtin_amdgcn_mfma_f32_16x16x32_bf16(af, b2, acc2, 0, 0, 0);
            acc3 = __builtin_amdgcn_mfma_f32_16x16x32_bf16(af, b3, acc3, 0, 0, 0);
            acc4 = __builtin_amdgcn_mfma_f32_16x16x32_bf16(af, bones, acc4, 0, 0, 0);
        }
    }

    // numerator partials: D layout col=lane&15, row=(lane>>4)*4+reg
    int orow = ib0 + w * 16 + kg * 4;
    float* np = nump + (size_t)kq * N * 64;
#pragma unroll
    for (int rr = 0; rr < 4; ++rr) {
        np[(size_t)(orow + rr) * 64 + 0 * 16 + r] = acc0[rr];
        np[(size_t)(orow + rr) * 64 + 1 * 16 + r] = acc1[rr];
        np[(size_t)(orow + rr) * 64 + 2 * 16 + r] = acc2[rr];
        np[(size_t)(orow + rr) * 64 + 3 * 16 + r] = acc3[rr];
    }
    if (r == 0) {
#pragma unroll
        for (int rr = 0; rr < 4; ++rr) denp_out[kq * N + orow + rr] = acc4[rr];
    }
}

// ---------------- out = elu(num/den), float4 per thread ----------------
__global__ __launch_bounds__(256) void k_final(const float* __restrict__ nump,
                                               const float* __restrict__ denp,
                                               float* __restrict__ out,
                                               int kqn) {
    int gid = blockIdx.x * 256 + threadIdx.x;   // 0 .. 131071
    int base = gid * 4;
    int i = base >> 6;
    float4 num = {0.f, 0.f, 0.f, 0.f};
    float den = 0.f;
    for (int q = 0; q < kqn; ++q) {
        float4 v = *(const float4*)(nump + (size_t)q * (N * 64) + base);
        num.x += v.x; num.y += v.y; num.z += v.z; num.w += v.w;
        den += denp[q * N + i];
    }
    float rd = 1.f / den;
    float4 o;
    o.x = num.x * rd; o.y = num.y * rd; o.z = num.z * rd; o.w = num.w * rd;
    o.x = o.x > 0.f ? o.x : __expf(o.x) - 1.f;
    o.y = o.y > 0.f ? o.y : __expf(o.y) - 1.f;
    o.z = o.z > 0.f ? o.z : __expf(o.z) - 1.f;
    o.w = o.w > 0.f ? o.w : __expf(o.w) - 1.f;
    *(float4*)(out + base) = o;
}

extern "C" void kernel_launch(void* const* d_in, const int* in_sizes, int n_in,
                              void* d_out, int out_size, void* d_ws, size_t ws_size,
                              hipStream_t stream) {
    const float* x   = (const float*)d_in[0];
    const int*   adj = (const int*)d_in[1];
    const float* w   = (const float*)d_in[2];
    const float* a   = (const float*)d_in[3];
    float* out = (float*)d_out;
    char*  ws  = (char*)d_ws;

    float*          h    = (float*)(ws + OFF_H);
    unsigned short* htf  = (unsigned short*)(ws + OFF_HT);
    float*          fs   = (float*)(ws + OFF_FS);
    float*          fd   = (float*)(ws + OFF_FD);
    float*          fdm  = (float*)(ws + OFF_FDMAX);
    u64*            bits = (u64*)(ws + OFF_BITS);
    float*          nump = (float*)(ws + OFF_NUM);

    size_t need8 = (size_t)OFF_NUM + 8ull * N * 64 * 4 + 8ull * N * 4;
    int KQ = (ws_size >= need8) ? 8 : 4;
    float* denp = nump + (size_t)KQ * N * 64;
    int jch = N / KQ;
    int ns  = jch / 32;
    int groups = jch / 256;

    k_linear<<<2048, 256, 0, stream>>>(x, w, a, h, fs, fd);
    k_frag<<<128, 256, 0, stream>>>(h, htf);
    k_fdmax<<<1, 256, 0, stream>>>(fd, fdm);
    k_pack<<<2048, 256, 0, stream>>>(adj, bits);
    k_mfma<<<KQ * 128, 256, 0, stream>>>(bits, fs, fd, fdm, htf, nump, denp,
                                         jch, ns, groups);
    k_final<<<512, 256, 0, stream>>>(nump, denp, out, KQ);
}

// Round 10
// 461.240 us; speedup vs baseline: 1.1449x; 1.0849x over previous
//
#include <hip/hip_runtime.h>
#include <hip/hip_bf16.h>

#define N 8192
#define IN_C 256
#define OUT_C 64
#define ALPHA 0.2f
#define L2E 1.44269504f
// KQ hardcoded to 8 (ws = 1 GiB confirmed by harness fill WRITE_SIZE)
#define KQ 8
#define JCH 1024       // N/KQ   cols per block
#define NS 32          // JCH/32 k-steps
#define GROUPS 4       // JCH/256
#define STRIDEU 19     // u64 per bits-row; odd -> 16 rows hit 16 distinct banks

typedef short bf16x8 __attribute__((ext_vector_type(8)));
typedef float f32x4 __attribute__((ext_vector_type(4)));
typedef unsigned long long u64;

// ---- ws layout (bytes) ----
#define OFF_H      0u            // f32  [8192][64]    h = x@w
#define OFF_HT     2097152u      // bf16 [256*4*64*8]  h in MFMA B-fragment order (1 MB)
#define OFF_FS     3145728u      // f32  [8192]        f_src
#define OFF_FD     3178496u      // f32  [8192]        f_dst
#define OFF_FDMAX  3211264u      // f32  [1]
#define OFF_NUM    3211520u      // f32  [8][8192][64] partial numerators, den follows

// ---------------- h = x @ w  (+ fused f_src/f_dst) ----------------
__global__ __launch_bounds__(256) void k_linear(const float* __restrict__ x,
                                                const float* __restrict__ w,
                                                const float* __restrict__ a,
                                                float* __restrict__ h,
                                                float* __restrict__ fs,
                                                float* __restrict__ fd) {
    __shared__ float wl[IN_C * OUT_C];
    int t = threadIdx.x;
    for (int idx = t; idx < IN_C * OUT_C; idx += 256) wl[idx] = w[idx];
    __syncthreads();
    int i = blockIdx.x * 4 + (t >> 6);
    int c = t & 63;
    const float* xr = x + (size_t)i * IN_C;
    float acc = 0.f;
#pragma unroll 8
    for (int k = 0; k < IN_C; ++k) acc = fmaf(xr[k], wl[k * 64 + c], acc);
    h[(size_t)i * 64 + c] = acc;
    float s = acc * a[c];
    float d = acc * a[64 + c];
#pragma unroll
    for (int off = 32; off > 0; off >>= 1) {
        s += __shfl_xor(s, off, 64);
        d += __shfl_xor(d, off, 64);
    }
    if (c == 0) { fs[i] = s; fd[i] = d; }
}

// ---------------- htf: h in MFMA B-fragment order ----------------
// htf[((ks*4 + ct)*64 + lane)*8 + e] = bf16(h[ks*32 + (lane>>4)*8 + e][ct*16 + (lane&15)])
__global__ __launch_bounds__(256) void k_frag(const float* __restrict__ h,
                                              unsigned short* __restrict__ htf) {
    __shared__ float lds[64 * 65];
    int t = threadIdx.x;
    int i0 = blockIdx.x * 64;
#pragma unroll
    for (int k = 0; k < 16; ++k) {
        int idx = k * 256 + t;
        int il = idx >> 6, c = idx & 63;
        lds[c * 65 + il] = h[(size_t)(i0 + il) * 64 + c];
    }
    __syncthreads();
    int l = t & 63;
    int ct = t >> 6;
    int r = l & 15, kg = l >> 4;
    int ch = ct * 16 + r;
#pragma unroll
    for (int ksl = 0; ksl < 2; ++ksl) {
        int ks = blockIdx.x * 2 + ksl;
        int n0 = ksl * 32 + kg * 8;
        bf16x8 v;
#pragma unroll
        for (int e = 0; e < 8; ++e) {
            __hip_bfloat16 hb = __float2bfloat16(lds[ch * 65 + n0 + e]);
            union { __hip_bfloat16 b; short s16; } u; u.b = hb;
            v[e] = u.s16;
        }
        *(bf16x8*)(htf + ((size_t)(ks * 4 + ct) * 64 + l) * 8) = v;
    }
}

// ---------------- fd_max ----------------
__global__ __launch_bounds__(256) void k_fdmax(const float* __restrict__ fd,
                                               float* __restrict__ out) {
    __shared__ float red[256];
    int t = threadIdx.x;
    float m = -3.4e38f;
    for (int j = t; j < N; j += 256) m = fmaxf(m, fd[j]);
    red[t] = m;
    __syncthreads();
    for (int s = 128; s > 0; s >>= 1) {
        if (t < s) red[t] = fmaxf(red[t], red[t + s]);
        __syncthreads();
    }
    if (t == 0) out[0] = red[0];
}

// ---------------- fused GAT kernel: pack(adj->LDS bits) + MFMA ----------------
// grid = 1024; bid = kq*128 + rb. Block: 64 rows x 1024 cols of adjacency.
// Phase 1: wave packs its 16 rows (4KB strip each) into LDS bitmask via
//   __ballot; 8 loads in flight (2-row unroll). Bit layout (r6/r9-verified):
//   mask m = col&3, bit = col_in_group>>2.
// Phase 2: B-tiles (4KB/k-step) stream global->LDS via global_load_lds,
//   4-buffer ring, 3 in flight, counted vmcnt(2) + s_barrier per k-step.
//   Weights from bits+fd (LDS); 5th MFMA vs ones B = denominator.
__device__ __forceinline__ void stage16(const unsigned short* g, unsigned short* lds) {
    __builtin_amdgcn_global_load_lds(
        (const __attribute__((address_space(1))) unsigned int*)g,
        (__attribute__((address_space(3))) unsigned int*)lds, 16, 0, 0);
}

__global__ __launch_bounds__(256, 4) void k_gat(
    const int* __restrict__ adj,
    const float* __restrict__ fsrc,
    const float* __restrict__ fdst,
    const float* __restrict__ fdmax_p,
    const unsigned short* __restrict__ htf,
    float* __restrict__ nump,
    float* __restrict__ denp_out) {
    __shared__ u64 bits[64 * STRIDEU];                   //  9728 B
    __shared__ float fd_lds[JCH];                        //  4096 B
    __shared__ alignas(16) unsigned short bufs[4][2048]; // 16384 B ring
    int bid = blockIdx.x;
    int rb = bid & 127, kq = bid >> 7;
    int t = threadIdx.x, w = t >> 6, l = t & 63;
    int r = l & 15, kg = l >> 4, kg2 = kg * 2;
    int ib0 = rb * 64;
    int i = ib0 + w * 16 + r;
    int j0 = kq * JCH;

    // fd slice -> LDS
    for (int u = t; u < JCH; u += 256) fd_lds[u] = fdst[j0 + u];

    // ---- phase 1: pack adjacency into LDS bits (2-row unroll, 8 loads deep) ----
#pragma unroll 1
    for (int rr = 0; rr < 16; rr += 2) {
        int rA = w * 16 + rr, rB = rA + 1;
        const int* sA = adj + (size_t)(ib0 + rA) * N + j0;
        const int* sB = adj + (size_t)(ib0 + rB) * N + j0;
        int4 va[GROUPS], vb[GROUPS];
#pragma unroll
        for (int g = 0; g < GROUPS; ++g) va[g] = *(const int4*)(sA + g * 256 + l * 4);
#pragma unroll
        for (int g = 0; g < GROUPS; ++g) vb[g] = *(const int4*)(sB + g * 256 + l * 4);
        u64 mA[16];
#pragma unroll
        for (int g = 0; g < GROUPS; ++g) {
            mA[g * 4 + 0] = __ballot(va[g].x > 0);
            mA[g * 4 + 1] = __ballot(va[g].y > 0);
            mA[g * 4 + 2] = __ballot(va[g].z > 0);
            mA[g * 4 + 3] = __ballot(va[g].w > 0);
        }
        if (l == 0) {
            u64* p = &bits[rA * STRIDEU];
#pragma unroll
            for (int q = 0; q < 16; ++q) p[q] = mA[q];
        }
        u64 mB[16];
#pragma unroll
        for (int g = 0; g < GROUPS; ++g) {
            mB[g * 4 + 0] = __ballot(vb[g].x > 0);
            mB[g * 4 + 1] = __ballot(vb[g].y > 0);
            mB[g * 4 + 2] = __ballot(vb[g].z > 0);
            mB[g * 4 + 3] = __ballot(vb[g].w > 0);
        }
        if (l == 0) {
            u64* p = &bits[rB * STRIDEU];
#pragma unroll
            for (int q = 0; q < 16; ++q) p[q] = mB[q];
        }
    }
    __syncthreads();

    // ---- phase 2: MFMA with LDS ring pipeline ----
    float fs  = fsrc[i];
    float fdm = *fdmax_p;
    float e0  = fs + fdm;
    float m   = fmaxf(e0, ALPHA * e0);   // row-wise softmax shift (monotone in fd)
    float mL  = m * L2E;

    int ks0 = j0 >> 5;
    stage16(htf + ((size_t)(ks0 + 0) * 2048 + t * 8), &bufs[0][w * 512]);
    stage16(htf + ((size_t)(ks0 + 1) * 2048 + t * 8), &bufs[1][w * 512]);
    stage16(htf + ((size_t)(ks0 + 2) * 2048 + t * 8), &bufs[2][w * 512]);

    bf16x8 bones;
#pragma unroll
    for (int e = 0; e < 8; ++e) bones[e] = (short)0x3F80;  // bf16 1.0

    f32x4 acc0 = {0.f,0.f,0.f,0.f}, acc1 = {0.f,0.f,0.f,0.f};
    f32x4 acc2 = {0.f,0.f,0.f,0.f}, acc3 = {0.f,0.f,0.f,0.f};
    f32x4 acc4 = {0.f,0.f,0.f,0.f};

    int rowL = w * 16 + r;
#pragma unroll 1
    for (int g = 0; g < GROUPS; ++g) {
        const u64* mp = &bits[rowL * STRIDEU + g * 4];
        u64 m0 = mp[0], m1 = mp[1], m2 = mp[2], m3 = mp[3];
        u64 msel[4] = {m0, m1, m2, m3};
#pragma unroll
        for (int k8 = 0; k8 < 8; ++k8) {
            int ks = g * 8 + k8;
            if (ks < NS - 2)       asm volatile("s_waitcnt vmcnt(2)" ::: "memory");
            else if (ks == NS - 2) asm volatile("s_waitcnt vmcnt(1)" ::: "memory");
            else                   asm volatile("s_waitcnt vmcnt(0)" ::: "memory");
            asm volatile("s_barrier" ::: "memory");
            if (ks + 3 < NS)
                stage16(htf + ((size_t)(ks0 + ks + 3) * 2048 + t * 8),
                        &bufs[(ks + 3) & 3][w * 512]);

            const unsigned short* bp = &bufs[ks & 3][0];
            bf16x8 b0 = *(const bf16x8*)(bp + (0 * 64 + l) * 8);
            bf16x8 b1 = *(const bf16x8*)(bp + (1 * 64 + l) * 8);
            bf16x8 b2 = *(const bf16x8*)(bp + (2 * 64 + l) * 8);
            bf16x8 b3 = *(const bf16x8*)(bp + (3 * 64 + l) * 8);
            float4 fd0 = *(const float4*)(fd_lds + ks * 32 + kg * 8);
            float4 fd1 = *(const float4*)(fd_lds + ks * 32 + kg * 8 + 4);
            float fdv[8] = {fd0.x, fd0.y, fd0.z, fd0.w, fd1.x, fd1.y, fd1.z, fd1.w};
            bf16x8 af;
#pragma unroll
            for (int e = 0; e < 8; ++e) {
                // col in group = k8*32 + kg*8 + e; mask = e&3, bit = k8*8 + kg*2 + (e>>2)
                int sh = k8 * 8 + kg2 + (e >> 2);
                unsigned bit = (unsigned)(msel[e & 3] >> sh) & 1u;
                float ee = fs + fdv[e];
                float lv = fmaxf(ee, ALPHA * ee);          // leaky-relu
                float a2 = __builtin_fmaf(lv, L2E, -mL);   // (l - m)*log2e
                float wt = __builtin_amdgcn_exp2f(a2);     // (0,1]
                wt = bit ? wt : 0.f;
                __hip_bfloat16 hb = __float2bfloat16(wt);
                union { __hip_bfloat16 b; short s16; } u; u.b = hb;
                af[e] = u.s16;
            }
            acc0 = __builtin_amdgcn_mfma_f32_16x16x32_bf16(af, b0, acc0, 0, 0, 0);
            acc1 = __builtin_amdgcn_mfma_f32_16x16x32_bf16(af, b1, acc1, 0, 0, 0);
            acc2 = __builtin_amdgcn_mfma_f32_16x16x32_bf16(af, b2, acc2, 0, 0, 0);
            acc3 = __builtin_amdgcn_mfma_f32_16x16x32_bf16(af, b3, acc3, 0, 0, 0);
            acc4 = __builtin_amdgcn_mfma_f32_16x16x32_bf16(af, bones, acc4, 0, 0, 0);
        }
    }

    // numerator partials: D layout col=lane&15, row=(lane>>4)*4+reg
    int orow = ib0 + w * 16 + kg * 4;
    float* np = nump + (size_t)kq * N * 64;
#pragma unroll
    for (int rr = 0; rr < 4; ++rr) {
        np[(size_t)(orow + rr) * 64 + 0 * 16 + r] = acc0[rr];
        np[(size_t)(orow + rr) * 64 + 1 * 16 + r] = acc1[rr];
        np[(size_t)(orow + rr) * 64 + 2 * 16 + r] = acc2[rr];
        np[(size_t)(orow + rr) * 64 + 3 * 16 + r] = acc3[rr];
    }
    if (r == 0) {
#pragma unroll
        for (int rr = 0; rr < 4; ++rr) denp_out[kq * N + orow + rr] = acc4[rr];
    }
}

// ---------------- out = elu(num/den), float4 per thread ----------------
__global__ __launch_bounds__(256) void k_final(const float* __restrict__ nump,
                                               const float* __restrict__ denp,
                                               float* __restrict__ out) {
    int gid = blockIdx.x * 256 + threadIdx.x;   // 0 .. 131071
    int base = gid * 4;
    int i = base >> 6;
    float4 num = {0.f, 0.f, 0.f, 0.f};
    float den = 0.f;
#pragma unroll
    for (int q = 0; q < KQ; ++q) {
        float4 v = *(const float4*)(nump + (size_t)q * (N * 64) + base);
        num.x += v.x; num.y += v.y; num.z += v.z; num.w += v.w;
        den += denp[q * N + i];
    }
    float rd = 1.f / den;
    float4 o;
    o.x = num.x * rd; o.y = num.y * rd; o.z = num.z * rd; o.w = num.w * rd;
    o.x = o.x > 0.f ? o.x : __expf(o.x) - 1.f;
    o.y = o.y > 0.f ? o.y : __expf(o.y) - 1.f;
    o.z = o.z > 0.f ? o.z : __expf(o.z) - 1.f;
    o.w = o.w > 0.f ? o.w : __expf(o.w) - 1.f;
    *(float4*)(out + base) = o;
}

extern "C" void kernel_launch(void* const* d_in, const int* in_sizes, int n_in,
                              void* d_out, int out_size, void* d_ws, size_t ws_size,
                              hipStream_t stream) {
    const float* x   = (const float*)d_in[0];
    const int*   adj = (const int*)d_in[1];
    const float* w   = (const float*)d_in[2];
    const float* a   = (const float*)d_in[3];
    float* out = (float*)d_out;
    char*  ws  = (char*)d_ws;

    float*          h    = (float*)(ws + OFF_H);
    unsigned short* htf  = (unsigned short*)(ws + OFF_HT);
    float*          fs   = (float*)(ws + OFF_FS);
    float*          fd   = (float*)(ws + OFF_FD);
    float*          fdm  = (float*)(ws + OFF_FDMAX);
    float*          nump = (float*)(ws + OFF_NUM);
    float*          denp = nump + (size_t)KQ * N * 64;

    k_linear<<<2048, 256, 0, stream>>>(x, w, a, h, fs, fd);
    k_frag<<<128, 256, 0, stream>>>(h, htf);
    k_fdmax<<<1, 256, 0, stream>>>(fd, fdm);
    k_gat<<<KQ * 128, 256, 0, stream>>>(adj, fs, fd, fdm, htf, nump, denp);
    k_final<<<512, 256, 0, stream>>>(nump, denp, out);
}